// Round 7
// baseline (65.836 us; speedup 1.0000x reference)
//
#include <hip/hip_runtime.h>
#include <hip/hip_bf16.h>

// ---------------------------------------------------------------------------
// PGNN layer: out = mean_{e: dst[e]=i} relu(concat(F,A)[src[e]] @ W + b)
// Pipeline per call (all on `stream`, graph-capture safe) — 3 kernels:
//   K0 wbt          : WbTf = bf16(W^T) in MFMA-fragment order; zero bcur
//   K1 fused        : blocks 0..255     -> SINGLE-PASS edge partition into
//                     FIXED 1024-slot bucket regions (edges buffered in regs,
//                     LDS histogram, ONE global atomic per block-bucket).
//                     (r4 lesson: per-edge global atomics+2B stores = 66 µs
//                     disaster — keep atomics LDS-aggregated.)
//                     blocks 256..1037  -> hb = bf16(relu([F|A] @ W + b)),
//                     TWO adjacent 32-row tiles per block: B-fragments/bias
//                     loaded once, tile-1 staging issued before tile-0 MFMA
//                     (r5: -1.8 µs). Coalesced float4 -> LDS staging -> MFMA
//                     (r1 lesson: direct per-lane fragment loads are
//                     512B-strided — staging is cheaper). NOT 4 tiles: grid
//                     would drop below 2 blocks/CU (r5 post-mortem).
//   K2 bucket_agg   : per bucket (32 nodes): ONE-PASS direct binning into
//                     fixed 64-slot stride-65 LDS bins (r6: neutral vs
//                     hist+scan but simpler; stride 65 keeps store bank
//                     conflicts <=2-way), then ONE 16-lane GROUP PER NODE
//                     (r7: kills the 8x shfl_xor cross-group reduce + the
//                     divergent g==0 store) with 4 independent dwordx4
//                     gather chains and PACKED f32x2 (v_pk_add_f32)
//                     accumulation (r7: 4->3 VALU per gathered word).
//                     (r2 lesson: single full-row pass, L3 serves L2 misses;
//                     slab passes regress — per-XCD L2s replicate. r3
//                     lesson: gather latency is TLP-hidden.)
//     (bucket deg ~ Binom(800k, 32/50k): mean 512, sigma 22.6; CAP=1024 is
//      +22 sigma. node deg ~ Binom(800k, 1/50k): mean 16, sigma 4; DCAP=64
//      is +12 sigma — guarded writes make overflow memory-safe.)
// ---------------------------------------------------------------------------

#define N_NODES 50000
#define N_EDGES 800000
#define HID 128
#define FDIM 128
#define ADIM 64
#define KDIM 192

#define BKT_SH 5
#define BKT_NODES 32
#define NBUCKETS ((N_NODES + BKT_NODES - 1) / BKT_NODES)   // 1563
#define CAP 1024                                           // fixed region slots
#define DCAP 64                                            // per-node bin slots
#define SS_LD 65                                           // padded bin stride
#define PC_NBLK 256
#define PC_CHUNK ((N_EDGES + PC_NBLK - 1) / PC_NBLK)       // 3125
#define EPT 13                                             // 13*256=3328 >= 3125
#define GEMM_NBLK ((N_NODES + 63) / 64)                    // 782 (2 tiles/block)
#define SA_LD 200                                          // padded LDS row (bf16)

typedef __attribute__((ext_vector_type(8))) short short8;
typedef __attribute__((ext_vector_type(4))) float f32x4;
typedef __attribute__((ext_vector_type(2))) float f32x2;
typedef __attribute__((ext_vector_type(4))) unsigned int u32x4;

__device__ inline unsigned short f2bf(float f) {
  unsigned u = __float_as_uint(f);
  u += 0x7FFFu + ((u >> 16) & 1u);   // RNE
  return (unsigned short)(u >> 16);
}
__device__ inline unsigned pk2bf(float a, float b) {
  return (unsigned)f2bf(a) | ((unsigned)f2bf(b) << 16);
}
// one u32 (2 packed bf16) -> f32x2 {lo, hi}; adds then use v_pk_add_f32
__device__ inline f32x2 bfpair(unsigned w) {
  union { unsigned u[2]; f32x2 f; } c;
  c.u[0] = w << 16;
  c.u[1] = w & 0xFFFF0000u;
  return c.f;
}

// K0: WbTf in fragment order [wn][nt][kk][lane][8]; block 0 zeroes bcur.
__global__ __launch_bounds__(256) void wbt_kernel(
    const float* __restrict__ W, unsigned short* __restrict__ WbTf,
    int* __restrict__ bcur) {
  if (blockIdx.x == 0) {
    for (int i = threadIdx.x; i < NBUCKETS; i += 256) bcur[i] = 0;
  }
  int idx = blockIdx.x * 256 + threadIdx.x;
  if (idx >= 2 * 4 * 6 * 64 * 8) return;
  int j = idx & 7;
  int lane = (idx >> 3) & 63;
  int frag = idx >> 9;          // 0..47
  int kk = frag % 6, p = frag / 6;
  int wn = p >> 2, nt = p & 3;
  int col = wn * 64 + nt * 16 + (lane & 15);
  int k = kk * 32 + (lane >> 4) * 8 + j;
  WbTf[idx] = f2bf(W[k * HID + col]);
}

// K1: fused. Blocks 0..PC_NBLK-1: single-pass partition. Rest: MFMA GEMM x2.
#define SMEM_BYTES (32 * SA_LD * 2)   // 12800 >= 2*NBUCKETS*4 = 12504
__global__ __launch_bounds__(256) void gemm_pscatter_kernel(
    const float* __restrict__ F, const float* __restrict__ A,
    const unsigned short* __restrict__ WbTf, const float* __restrict__ bias,
    unsigned short* __restrict__ hb,
    const int* __restrict__ src, const int* __restrict__ dst,
    int* __restrict__ bcur, unsigned* __restrict__ edata, int nrows) {
  __shared__ __align__(16) char smem_raw[SMEM_BYTES];

  if (blockIdx.x < PC_NBLK) {
    // ---- partition path: single pass, edges buffered in registers ----
    int* lh = (int*)smem_raw;            // per-bucket: count, then global base
    int* lc = lh + NBUCKETS;             // running local cursor
    int bp = blockIdx.x;
    for (int i = threadIdx.x; i < NBUCKETS; i += 256) lh[i] = 0;
    __syncthreads();
    int base = bp * PC_CHUNK;
    int end = base + PC_CHUNK; if (end > N_EDGES) end = N_EDGES;
    int rd[EPT], rs[EPT];
#pragma unroll
    for (int k = 0; k < EPT; ++k) {
      int j = base + threadIdx.x + k * 256;
      if (j < end) {
        rd[k] = dst[j];
        rs[k] = src[j];
        atomicAdd(&lh[rd[k] >> BKT_SH], 1);
      } else {
        rd[k] = -1;
      }
    }
    __syncthreads();
    for (int i = threadIdx.x; i < NBUCKETS; i += 256) {
      int c = lh[i];
      lh[i] = c ? atomicAdd(&bcur[i], c) : 0;   // reserve contiguous slice
      lc[i] = 0;
    }
    __syncthreads();
#pragma unroll
    for (int k = 0; k < EPT; ++k) {
      if (rd[k] >= 0) {
        int bk = rd[k] >> BKT_SH, dl = rd[k] & (BKT_NODES - 1);
        int p = lh[bk] + atomicAdd(&lc[bk], 1);
        if (p < CAP)   // 22-sigma guard: memory safety on impossible overflow
          edata[(bk << 10) + p] = (unsigned)rs[k] | ((unsigned)dl << 16);
      }
    }
    return;
  }

  // ---- gemm path: 2 adjacent 32-row tiles, B-frags/bias loaded once ----
  unsigned short* sA = (unsigned short*)smem_raw;  // [32][SA_LD]
  const int gblk = blockIdx.x - PC_NBLK;
  const int tid = threadIdx.x;
  const int lane = tid & 63;
  const int wave = tid >> 6;
  const int wm = wave >> 1, wn = wave & 1;
  const int l15 = lane & 15, lg = lane >> 4;
  const int br0 = gblk * 64;
  const int br1 = br0 + 32;

  // Stage one 32-row tile: coalesced float4 loads, cvt fp32->bf16, b64 LDS
  // writes. F part: 1024 float4 (4/thread); A part: 512 float4 (2/thread).
  auto stage = [&](int rowbase) {
#pragma unroll
    for (int it = 0; it < 4; ++it) {
      int i = tid + it * 256;
      int row = i >> 5, c4 = (i & 31) * 4;
      int crow = rowbase + row; crow = crow < nrows ? crow : (nrows - 1);
      float4 v = *(const float4*)(F + (size_t)crow * FDIM + c4);
      *(uint2*)(sA + row * SA_LD + c4) = make_uint2(pk2bf(v.x, v.y), pk2bf(v.z, v.w));
    }
#pragma unroll
    for (int it = 0; it < 2; ++it) {
      int i = tid + it * 256;
      int row = i >> 4, c4 = (i & 15) * 4;
      int crow = rowbase + row; crow = crow < nrows ? crow : (nrows - 1);
      float4 v = *(const float4*)(A + (size_t)crow * ADIM + c4);
      *(uint2*)(sA + row * SA_LD + FDIM + c4) = make_uint2(pk2bf(v.x, v.y), pk2bf(v.z, v.w));
    }
  };

  stage(br0);

  // B fragments: fully coalesced (fragment-ordered table, L2-resident);
  // loaded ONCE, reused by both tiles.
  short8 Bf[24];
#pragma unroll
  for (int nt = 0; nt < 4; ++nt)
#pragma unroll
    for (int kk = 0; kk < 6; ++kk)
      Bf[nt * 6 + kk] = *(const short8*)(
          WbTf + ((((wn * 4 + nt) * 6 + kk) << 9) + (lane << 3)));

  float bv[4];
#pragma unroll
  for (int nt = 0; nt < 4; ++nt) bv[nt] = bias[wn * 64 + nt * 16 + l15];

  __syncthreads();

  // A fragments tile0 from LDS (ds_read_b128)
  const int rowl = wm * 16 + l15;
  short8 Af[6];
#pragma unroll
  for (int kk = 0; kk < 6; ++kk)
    Af[kk] = *(const short8*)(sA + rowl * SA_LD + kk * 32 + lg * 8);

  const bool has2 = (br1 < nrows);          // block-uniform
  if (has2) {
    __syncthreads();                        // all Af0 reads done
    stage(br1);                             // loads in flight under tile0 MFMA
  }

  auto compute_store = [&](const short8* Afp, int rowbase) {
    f32x4 acc[4] = {{0,0,0,0},{0,0,0,0},{0,0,0,0},{0,0,0,0}};
#pragma unroll
    for (int nt = 0; nt < 4; ++nt)
#pragma unroll
      for (int kk = 0; kk < 6; ++kk)
        acc[nt] = __builtin_amdgcn_mfma_f32_16x16x32_bf16(
            Afp[kk], Bf[nt * 6 + kk], acc[nt], 0, 0, 0);
    const int rb = rowbase + wm * 16;
#pragma unroll
    for (int nt = 0; nt < 4; ++nt) {
      int col = wn * 64 + nt * 16 + l15;
#pragma unroll
      for (int q = 0; q < 4; ++q) {
        int row = rb + lg * 4 + q;
        if (row < nrows) {
          float v = fmaxf(acc[nt][q] + bv[nt], 0.f);
          hb[(size_t)row * HID + col] = f2bf(v);
        }
      }
    }
  };

  compute_store(Af, br0);

  if (has2) {
    __syncthreads();                        // tile1 LDS writes visible
    short8 Af1[6];
#pragma unroll
    for (int kk = 0; kk < 6; ++kk)
      Af1[kk] = *(const short8*)(sA + rowl * SA_LD + kk * 32 + lg * 8);
    compute_store(Af1, br1);
  }
}

// K2: one-pass binning into stride-65 LDS bins; one 16-lane group per node,
// packed f32x2 accumulation, no cross-lane reduce, full-width stores.
#define EPT_A (CAP / 256)   // 4
__global__ __launch_bounds__(256) void bucket_agg_kernel(
    const unsigned short* __restrict__ hb, const int* __restrict__ bcur,
    const unsigned* __restrict__ edata, float* __restrict__ out) {
  int b = blockIdx.x;
  int nbase = b << BKT_SH;
  int nloc = N_NODES - nbase; if (nloc > BKT_NODES) nloc = BKT_NODES;
  int gb = b << 10;
  int cnt = bcur[b]; cnt = cnt < CAP ? cnt : CAP;
  int t = threadIdx.x, lane = t & 63, wave = t >> 6;
  int g = lane >> 4, l16 = lane & 15;
  int gg = wave * 4 + g;                      // group id 0..15, one NODE each

  __shared__ unsigned short ss[BKT_NODES * SS_LD];   // 32 bins, stride 65
  __shared__ int lcnt[BKT_NODES];

  if (t < BKT_NODES) lcnt[t] = 0;
  __syncthreads();
  // ONE pass: load edge, claim slot, store into bin. Bin stride 65 ->
  // store bank = ((dl+p)>>1)&31: <=2-way conflict (free).
#pragma unroll
  for (int k = 0; k < EPT_A; ++k) {
    int j = t + k * 256;
    if (j < cnt) {
      unsigned e = edata[gb + j];
      int dl = e >> 16;
      int p = atomicAdd(&lcnt[dl], 1);
      if (p < DCAP)   // +12-sigma guard: memory-safe on impossible overflow
        ss[dl * SS_LD + p] = (unsigned short)(e & 0xFFFFu);
    }
  }
  __syncthreads();

  const unsigned short* hbl = hb + l16 * 8;   // lane's 16B column slice
  for (int n = gg; n < nloc; n += 16) {       // 2 nodes per group
    int d = lcnt[n];                          // true degree (divisor)
    int dc = d < DCAP ? d : DCAP;
    int s0 = n * SS_LD, s1 = s0 + dc;
    f32x2 acc2[4] = {{0, 0}, {0, 0}, {0, 0}, {0, 0}};
    int j = s0;
    // 4 independent dwordx4 gather chains (consecutive bin slots)
    for (; j + 3 < s1; j += 4) {
      int e0 = ss[j], e1 = ss[j + 1], e2 = ss[j + 2], e3 = ss[j + 3];
      u32x4 v0 = *(const u32x4*)(hbl + (size_t)e0 * HID);
      u32x4 v1 = *(const u32x4*)(hbl + (size_t)e1 * HID);
      u32x4 v2 = *(const u32x4*)(hbl + (size_t)e2 * HID);
      u32x4 v3 = *(const u32x4*)(hbl + (size_t)e3 * HID);
#pragma unroll
      for (int i = 0; i < 4; ++i)
        acc2[i] += (bfpair(v0[i]) + bfpair(v1[i]))
                 + (bfpair(v2[i]) + bfpair(v3[i]));
    }
    for (; j < s1; ++j) {
      int e0 = ss[j];
      u32x4 v0 = *(const u32x4*)(hbl + (size_t)e0 * HID);
#pragma unroll
      for (int i = 0; i < 4; ++i) acc2[i] += bfpair(v0[i]);
    }
    float inv = 1.0f / (float)(d > 1 ? d : 1);
    float* po = out + (size_t)(nbase + n) * HID + l16 * 8;
    // acc2[i] = {col 2i, col 2i+1} within the lane's 8 columns
    *(float4*)po = make_float4(acc2[0].x * inv, acc2[0].y * inv,
                               acc2[1].x * inv, acc2[1].y * inv);
    *(float4*)(po + 4) = make_float4(acc2[2].x * inv, acc2[2].y * inv,
                                     acc2[3].x * inv, acc2[3].y * inv);
  }
}

extern "C" void kernel_launch(void* const* d_in, const int* in_sizes, int n_in,
                              void* d_out, int out_size, void* d_ws, size_t ws_size,
                              hipStream_t stream) {
  const float* F   = (const float*)d_in[0];  // [50000,128]
  const float* A   = (const float*)d_in[1];  // [50000,64]
  const float* W   = (const float*)d_in[2];  // [192,128]
  const float* b   = (const float*)d_in[3];  // [128]
  const int*   src = (const int*)d_in[4];    // [800000]
  const int*   dst = (const int*)d_in[5];    // [800000]
  float* out = (float*)d_out;                // [50000,128]

  char* ws = (char*)d_ws;
  size_t off = 0;
  auto alloc = [&](size_t bytes) {
    char* p = ws + off;
    off += (bytes + 255) & ~(size_t)255;
    return p;
  };
  unsigned short* hb   = (unsigned short*)alloc((size_t)N_NODES * HID * 2); // 12.8 MB
  unsigned short* WbTf = (unsigned short*)alloc((size_t)HID * KDIM * 2);    // 48 KB
  int* bcur = (int*)alloc((size_t)NBUCKETS * sizeof(int));
  unsigned* edata = (unsigned*)alloc((size_t)NBUCKETS * CAP * sizeof(unsigned)); // 6.4 MB
  (void)ws_size;

  wbt_kernel<<<(KDIM * HID + 255) / 256, 256, 0, stream>>>(W, WbTf, bcur);
  gemm_pscatter_kernel<<<PC_NBLK + GEMM_NBLK, 256, 0, stream>>>(
      F, A, WbTf, b, hb, src, dst, bcur, edata, N_NODES);
  bucket_agg_kernel<<<NBUCKETS, 256, 0, stream>>>(hb, bcur, edata, out);
}

// Round 10
// 64.828 us; speedup vs baseline: 1.0156x; 1.0156x over previous
//
#include <hip/hip_runtime.h>
#include <hip/hip_bf16.h>

// ---------------------------------------------------------------------------
// PGNN layer: out = mean_{e: dst[e]=i} relu(concat(F,A)[src[e]] @ W + b)
// Pipeline per call (all on `stream`, graph-capture safe) — 3 kernels:
//   K0 wbt          : WbTf = bf16(W^T) in MFMA-fragment order; zero bcur
//   K1 fused        : blocks 0..255     -> SINGLE-PASS edge partition into
//                     FIXED 1024-slot bucket regions (edges buffered in regs,
//                     LDS histogram, ONE global atomic per block-bucket).
//                     (r4 lesson: per-edge global atomics+2B stores = 66 µs
//                     disaster — keep atomics LDS-aggregated.)
//                     blocks 256..1037  -> hb = bf16(relu([F|A] @ W + b)),
//                     TWO adjacent 32-row tiles per block: B-fragments/bias
//                     loaded once, tile-1 staging issued before tile-0 MFMA
//                     (r5: -1.8 µs). Coalesced float4 -> LDS staging -> MFMA
//                     (r1 lesson: direct per-lane fragment loads are
//                     512B-strided — staging is cheaper). NOT 4 tiles: grid
//                     would drop below 2 blocks/CU (r5 post-mortem).
//   K2 bucket_agg   : per bucket (32 nodes): ONE-PASS direct binning into
//                     fixed 64-slot stride-65 LDS bins (r6), then per-node
//                     4x16-lane-group gather/mean, 4 independent dwordx4
//                     chains (r2: single full-row pass optimal — per-XCD L2s
//                     replicate; r3: gather latency TLP-hidden; r7: loop is
//                     cache-bound, not VALU — keep r6 reduce form).
//                     r10: NONTEMPORAL edata loads + out stores (streaming
//                     32 MB must not evict the hot 12.8 MB hb from L2).
//   r8/r9 lesson    : hipLaunchCooperativeKernel silently fails under this
//                     harness's stream capture (unchecked rc; signature:
//                     absmax == max|ref| with untouched output). Single
//                     fused cooperative kernel is NOT available — 3-dispatch
//                     structure is final.
//     (bucket deg ~ Binom(800k, 32/50k): mean 512, sigma 22.6; CAP=1024 is
//      +22 sigma. node deg ~ Binom(800k, 1/50k): mean 16, sigma 4; DCAP=64
//      is +12 sigma — guarded writes make overflow memory-safe.)
// ---------------------------------------------------------------------------

#define N_NODES 50000
#define N_EDGES 800000
#define HID 128
#define FDIM 128
#define ADIM 64
#define KDIM 192

#define BKT_SH 5
#define BKT_NODES 32
#define NBUCKETS ((N_NODES + BKT_NODES - 1) / BKT_NODES)   // 1563
#define CAP 1024                                           // fixed region slots
#define DCAP 64                                            // per-node bin slots
#define SS_LD 65                                           // padded bin stride
#define PC_NBLK 256
#define PC_CHUNK ((N_EDGES + PC_NBLK - 1) / PC_NBLK)       // 3125
#define EPT 13                                             // 13*256=3328 >= 3125
#define GEMM_NBLK ((N_NODES + 63) / 64)                    // 782 (2 tiles/block)
#define SA_LD 200                                          // padded LDS row (bf16)

typedef __attribute__((ext_vector_type(8))) short short8;
typedef __attribute__((ext_vector_type(4))) float f32x4;
typedef __attribute__((ext_vector_type(4))) unsigned int u32x4;

__device__ inline unsigned short f2bf(float f) {
  unsigned u = __float_as_uint(f);
  u += 0x7FFFu + ((u >> 16) & 1u);   // RNE
  return (unsigned short)(u >> 16);
}
__device__ inline unsigned pk2bf(float a, float b) {
  return (unsigned)f2bf(a) | ((unsigned)f2bf(b) << 16);
}
__device__ inline float bf2f(unsigned short s) {
  return __uint_as_float(((unsigned)s) << 16);
}

// K0: WbTf in fragment order [wn][nt][kk][lane][8]; block 0 zeroes bcur.
__global__ __launch_bounds__(256) void wbt_kernel(
    const float* __restrict__ W, unsigned short* __restrict__ WbTf,
    int* __restrict__ bcur) {
  if (blockIdx.x == 0) {
    for (int i = threadIdx.x; i < NBUCKETS; i += 256) bcur[i] = 0;
  }
  int idx = blockIdx.x * 256 + threadIdx.x;
  if (idx >= 2 * 4 * 6 * 64 * 8) return;
  int j = idx & 7;
  int lane = (idx >> 3) & 63;
  int frag = idx >> 9;          // 0..47
  int kk = frag % 6, p = frag / 6;
  int wn = p >> 2, nt = p & 3;
  int col = wn * 64 + nt * 16 + (lane & 15);
  int k = kk * 32 + (lane >> 4) * 8 + j;
  WbTf[idx] = f2bf(W[k * HID + col]);
}

// K1: fused. Blocks 0..PC_NBLK-1: single-pass partition. Rest: MFMA GEMM x2.
#define SMEM_BYTES (32 * SA_LD * 2)   // 12800 >= 2*NBUCKETS*4 = 12504
__global__ __launch_bounds__(256) void gemm_pscatter_kernel(
    const float* __restrict__ F, const float* __restrict__ A,
    const unsigned short* __restrict__ WbTf, const float* __restrict__ bias,
    unsigned short* __restrict__ hb,
    const int* __restrict__ src, const int* __restrict__ dst,
    int* __restrict__ bcur, unsigned* __restrict__ edata, int nrows) {
  __shared__ __align__(16) char smem_raw[SMEM_BYTES];

  if (blockIdx.x < PC_NBLK) {
    // ---- partition path: single pass, edges buffered in registers ----
    int* lh = (int*)smem_raw;            // per-bucket: count, then global base
    int* lc = lh + NBUCKETS;             // running local cursor
    int bp = blockIdx.x;
    for (int i = threadIdx.x; i < NBUCKETS; i += 256) lh[i] = 0;
    __syncthreads();
    int base = bp * PC_CHUNK;
    int end = base + PC_CHUNK; if (end > N_EDGES) end = N_EDGES;
    int rd[EPT], rs[EPT];
#pragma unroll
    for (int k = 0; k < EPT; ++k) {
      int j = base + threadIdx.x + k * 256;
      if (j < end) {
        rd[k] = dst[j];
        rs[k] = src[j];
        atomicAdd(&lh[rd[k] >> BKT_SH], 1);
      } else {
        rd[k] = -1;
      }
    }
    __syncthreads();
    for (int i = threadIdx.x; i < NBUCKETS; i += 256) {
      int c = lh[i];
      lh[i] = c ? atomicAdd(&bcur[i], c) : 0;   // reserve contiguous slice
      lc[i] = 0;
    }
    __syncthreads();
#pragma unroll
    for (int k = 0; k < EPT; ++k) {
      if (rd[k] >= 0) {
        int bk = rd[k] >> BKT_SH, dl = rd[k] & (BKT_NODES - 1);
        int p = lh[bk] + atomicAdd(&lc[bk], 1);
        if (p < CAP)   // 22-sigma guard: memory safety on impossible overflow
          edata[(bk << 10) + p] = (unsigned)rs[k] | ((unsigned)dl << 16);
      }
    }
    return;
  }

  // ---- gemm path: 2 adjacent 32-row tiles, B-frags/bias loaded once ----
  unsigned short* sA = (unsigned short*)smem_raw;  // [32][SA_LD]
  const int gblk = blockIdx.x - PC_NBLK;
  const int tid = threadIdx.x;
  const int lane = tid & 63;
  const int wave = tid >> 6;
  const int wm = wave >> 1, wn = wave & 1;
  const int l15 = lane & 15, lg = lane >> 4;
  const int br0 = gblk * 64;
  const int br1 = br0 + 32;

  // Stage one 32-row tile: coalesced float4 loads, cvt fp32->bf16, b64 LDS
  // writes. F part: 1024 float4 (4/thread); A part: 512 float4 (2/thread).
  auto stage = [&](int rowbase) {
#pragma unroll
    for (int it = 0; it < 4; ++it) {
      int i = tid + it * 256;
      int row = i >> 5, c4 = (i & 31) * 4;
      int crow = rowbase + row; crow = crow < nrows ? crow : (nrows - 1);
      float4 v = *(const float4*)(F + (size_t)crow * FDIM + c4);
      *(uint2*)(sA + row * SA_LD + c4) = make_uint2(pk2bf(v.x, v.y), pk2bf(v.z, v.w));
    }
#pragma unroll
    for (int it = 0; it < 2; ++it) {
      int i = tid + it * 256;
      int row = i >> 4, c4 = (i & 15) * 4;
      int crow = rowbase + row; crow = crow < nrows ? crow : (nrows - 1);
      float4 v = *(const float4*)(A + (size_t)crow * ADIM + c4);
      *(uint2*)(sA + row * SA_LD + FDIM + c4) = make_uint2(pk2bf(v.x, v.y), pk2bf(v.z, v.w));
    }
  };

  stage(br0);

  // B fragments: fully coalesced (fragment-ordered table, L2-resident);
  // loaded ONCE, reused by both tiles.
  short8 Bf[24];
#pragma unroll
  for (int nt = 0; nt < 4; ++nt)
#pragma unroll
    for (int kk = 0; kk < 6; ++kk)
      Bf[nt * 6 + kk] = *(const short8*)(
          WbTf + ((((wn * 4 + nt) * 6 + kk) << 9) + (lane << 3)));

  float bv[4];
#pragma unroll
  for (int nt = 0; nt < 4; ++nt) bv[nt] = bias[wn * 64 + nt * 16 + l15];

  __syncthreads();

  // A fragments tile0 from LDS (ds_read_b128)
  const int rowl = wm * 16 + l15;
  short8 Af[6];
#pragma unroll
  for (int kk = 0; kk < 6; ++kk)
    Af[kk] = *(const short8*)(sA + rowl * SA_LD + kk * 32 + lg * 8);

  const bool has2 = (br1 < nrows);          // block-uniform
  if (has2) {
    __syncthreads();                        // all Af0 reads done
    stage(br1);                             // loads in flight under tile0 MFMA
  }

  auto compute_store = [&](const short8* Afp, int rowbase) {
    f32x4 acc[4] = {{0,0,0,0},{0,0,0,0},{0,0,0,0},{0,0,0,0}};
#pragma unroll
    for (int nt = 0; nt < 4; ++nt)
#pragma unroll
      for (int kk = 0; kk < 6; ++kk)
        acc[nt] = __builtin_amdgcn_mfma_f32_16x16x32_bf16(
            Afp[kk], Bf[nt * 6 + kk], acc[nt], 0, 0, 0);
    const int rb = rowbase + wm * 16;
#pragma unroll
    for (int nt = 0; nt < 4; ++nt) {
      int col = wn * 64 + nt * 16 + l15;
#pragma unroll
      for (int q = 0; q < 4; ++q) {
        int row = rb + lg * 4 + q;
        if (row < nrows) {
          float v = fmaxf(acc[nt][q] + bv[nt], 0.f);
          hb[(size_t)row * HID + col] = f2bf(v);
        }
      }
    }
  };

  compute_store(Af, br0);

  if (has2) {
    __syncthreads();                        // tile1 LDS writes visible
    short8 Af1[6];
#pragma unroll
    for (int kk = 0; kk < 6; ++kk)
      Af1[kk] = *(const short8*)(sA + rowl * SA_LD + kk * 32 + lg * 8);
    compute_store(Af1, br1);
  }
}

// K2: one-pass binning into stride-65 LDS bins + gather/mean.
// r10: nontemporal edata loads + out stores (protect hb's L2 residency).
#define EPT_A (CAP / 256)   // 4
__global__ __launch_bounds__(256) void bucket_agg_kernel(
    const unsigned short* __restrict__ hb, const int* __restrict__ bcur,
    const unsigned* __restrict__ edata, float* __restrict__ out) {
  int b = blockIdx.x;
  int nbase = b << BKT_SH;
  int nloc = N_NODES - nbase; if (nloc > BKT_NODES) nloc = BKT_NODES;
  int gb = b << 10;
  int cnt = bcur[b]; cnt = cnt < CAP ? cnt : CAP;
  int t = threadIdx.x, lane = t & 63, wave = t >> 6;
  int g = lane >> 4, l16 = lane & 15;

  __shared__ unsigned short ss[BKT_NODES * SS_LD];   // 32 bins, stride 65
  __shared__ int lcnt[BKT_NODES];

  if (t < BKT_NODES) lcnt[t] = 0;
  __syncthreads();
  // ONE pass: load edge, claim slot, store into bin. Bin stride 65 ->
  // store bank = ((dl+p)>>1)&31: <=2-way conflict (free).
#pragma unroll
  for (int k = 0; k < EPT_A; ++k) {
    int j = t + k * 256;
    if (j < cnt) {
      unsigned e = __builtin_nontemporal_load(edata + gb + j);
      int dl = e >> 16;
      int p = atomicAdd(&lcnt[dl], 1);
      if (p < DCAP)   // +12-sigma guard: memory-safe on impossible overflow
        ss[dl * SS_LD + p] = (unsigned short)(e & 0xFFFFu);
    }
  }
  __syncthreads();

  const unsigned short* hbl = hb + l16 * 8;   // lane's 16B column slice
  for (int n = wave; n < nloc; n += 4) {
    int d = lcnt[n];                          // true degree (divisor)
    int dc = d < DCAP ? d : DCAP;
    int s0 = n * SS_LD, s1 = s0 + dc;
    float acc[8] = {0, 0, 0, 0, 0, 0, 0, 0};
    int j = s0 + g;
    // 4 independent full-row gather chains per 16-lane group
    for (; j + 12 < s1; j += 16) {
      int e0 = ss[j], e1 = ss[j + 4], e2 = ss[j + 8], e3 = ss[j + 12];
      u32x4 v0 = *(const u32x4*)(hbl + (size_t)e0 * HID);
      u32x4 v1 = *(const u32x4*)(hbl + (size_t)e1 * HID);
      u32x4 v2 = *(const u32x4*)(hbl + (size_t)e2 * HID);
      u32x4 v3 = *(const u32x4*)(hbl + (size_t)e3 * HID);
#pragma unroll
      for (int i = 0; i < 4; ++i) {
        unsigned w0 = v0[i], w1 = v1[i], w2 = v2[i], w3 = v3[i];
        acc[2 * i]     += (bf2f((unsigned short)(w0 & 0xFFFFu))
                         + bf2f((unsigned short)(w1 & 0xFFFFu)))
                        + (bf2f((unsigned short)(w2 & 0xFFFFu))
                         + bf2f((unsigned short)(w3 & 0xFFFFu)));
        acc[2 * i + 1] += (bf2f((unsigned short)(w0 >> 16))
                         + bf2f((unsigned short)(w1 >> 16)))
                        + (bf2f((unsigned short)(w2 >> 16))
                         + bf2f((unsigned short)(w3 >> 16)));
      }
    }
    for (; j < s1; j += 4) {
      int e0 = ss[j];
      u32x4 v0 = *(const u32x4*)(hbl + (size_t)e0 * HID);
#pragma unroll
      for (int i = 0; i < 4; ++i) {
        unsigned w0 = v0[i];
        acc[2 * i]     += bf2f((unsigned short)(w0 & 0xFFFFu));
        acc[2 * i + 1] += bf2f((unsigned short)(w0 >> 16));
      }
    }
#pragma unroll
    for (int i = 0; i < 8; ++i) {
      acc[i] += __shfl_xor(acc[i], 16, 64);
      acc[i] += __shfl_xor(acc[i], 32, 64);
    }
    if (g == 0) {
      float inv = 1.0f / (float)(d > 1 ? d : 1);
      float* po = out + (size_t)(nbase + n) * HID + l16 * 8;
      f32x4 o0 = {acc[0] * inv, acc[1] * inv, acc[2] * inv, acc[3] * inv};
      f32x4 o1 = {acc[4] * inv, acc[5] * inv, acc[6] * inv, acc[7] * inv};
      __builtin_nontemporal_store(o0, (f32x4*)po);
      __builtin_nontemporal_store(o1, (f32x4*)(po + 4));
    }
  }
}

extern "C" void kernel_launch(void* const* d_in, const int* in_sizes, int n_in,
                              void* d_out, int out_size, void* d_ws, size_t ws_size,
                              hipStream_t stream) {
  const float* F   = (const float*)d_in[0];  // [50000,128]
  const float* A   = (const float*)d_in[1];  // [50000,64]
  const float* W   = (const float*)d_in[2];  // [192,128]
  const float* b   = (const float*)d_in[3];  // [128]
  const int*   src = (const int*)d_in[4];    // [800000]
  const int*   dst = (const int*)d_in[5];    // [800000]
  float* out = (float*)d_out;                // [50000,128]

  char* ws = (char*)d_ws;
  size_t off = 0;
  auto alloc = [&](size_t bytes) {
    char* p = ws + off;
    off += (bytes + 255) & ~(size_t)255;
    return p;
  };
  unsigned short* hb   = (unsigned short*)alloc((size_t)N_NODES * HID * 2); // 12.8 MB
  unsigned short* WbTf = (unsigned short*)alloc((size_t)HID * KDIM * 2);    // 48 KB
  int* bcur = (int*)alloc((size_t)NBUCKETS * sizeof(int));
  unsigned* edata = (unsigned*)alloc((size_t)NBUCKETS * CAP * sizeof(unsigned)); // 6.4 MB
  (void)ws_size;

  wbt_kernel<<<(KDIM * HID + 255) / 256, 256, 0, stream>>>(W, WbTf, bcur);
  gemm_pscatter_kernel<<<PC_NBLK + GEMM_NBLK, 256, 0, stream>>>(
      F, A, WbTf, b, hb, src, dst, bcur, edata, N_NODES);
  bucket_agg_kernel<<<NBUCKETS, 256, 0, stream>>>(hb, bcur, edata, out);
}

// Round 11
// 61.335 us; speedup vs baseline: 1.0734x; 1.0570x over previous
//
#include <hip/hip_runtime.h>
#include <hip/hip_bf16.h>

// ---------------------------------------------------------------------------
// PGNN layer: out = mean_{e: dst[e]=i} relu(concat(F,A)[src[e]] @ W + b)
// Pipeline per call (all on `stream`, graph-capture safe) — 3 kernels:
//   K0 wbt          : WbTf = bf16(W^T) in MFMA-fragment order; zero bcur
//   K1 fused        : blocks 0..255     -> SINGLE-PASS edge partition into
//                     FIXED 1024-slot bucket regions (edges buffered in regs,
//                     LDS histogram, ONE global atomic per block-bucket).
//                     (r4 lesson: per-edge global atomics+2B stores = 66 µs
//                     disaster — keep atomics LDS-aggregated.)
//                     blocks 256..1037  -> hb = bf16(relu([F|A] @ W + b)),
//                     TWO adjacent 32-row tiles per block: B-fragments/bias
//                     loaded once, tile-1 staging issued before tile-0 MFMA
//                     (r5: -1.8 µs). Coalesced float4 -> LDS staging -> MFMA
//                     (r1 lesson: direct per-lane fragment loads are
//                     512B-strided — staging is cheaper). NOT 4 tiles: grid
//                     would drop below 2 blocks/CU (r5 post-mortem).
//                     r11: fp32->bf16 via HW v_cvt_pk_bf16_f32 inline asm
//                     (1 VALU per 2 values, RNE — replaces ~4-9 op manual
//                     bit-RNE; no builtin exists on gfx950).
//   K2 bucket_agg   : per bucket (32 nodes): ONE-PASS direct binning into
//                     fixed 64-slot stride-65 LDS bins (r6), then per-node
//                     4x16-lane-group gather/mean, 4 independent dwordx4
//                     chains (r2: single full-row pass optimal — per-XCD L2s
//                     replicate; r3: gather latency TLP-hidden; r7: loop is
//                     cache-bound, not VALU — keep r6 reduce form).
//                     r10: NONTEMPORAL edata loads + out stores (keep 32 MB
//                     streaming from evicting the hot 12.8 MB hb in L2).
//   r8/r9 lesson    : hipLaunchCooperativeKernel silently fails under this
//                     harness's stream capture (unchecked rc; signature:
//                     absmax == max|ref| with untouched output). Single
//                     fused cooperative kernel is NOT available — 3-dispatch
//                     structure is final.
//     (bucket deg ~ Binom(800k, 32/50k): mean 512, sigma 22.6; CAP=1024 is
//      +22 sigma. node deg ~ Binom(800k, 1/50k): mean 16, sigma 4; DCAP=64
//      is +12 sigma — guarded writes make overflow memory-safe.)
// ---------------------------------------------------------------------------

#define N_NODES 50000
#define N_EDGES 800000
#define HID 128
#define FDIM 128
#define ADIM 64
#define KDIM 192

#define BKT_SH 5
#define BKT_NODES 32
#define NBUCKETS ((N_NODES + BKT_NODES - 1) / BKT_NODES)   // 1563
#define CAP 1024                                           // fixed region slots
#define DCAP 64                                            // per-node bin slots
#define SS_LD 65                                           // padded bin stride
#define PC_NBLK 256
#define PC_CHUNK ((N_EDGES + PC_NBLK - 1) / PC_NBLK)       // 3125
#define EPT 13                                             // 13*256=3328 >= 3125
#define GEMM_NBLK ((N_NODES + 63) / 64)                    // 782 (2 tiles/block)
#define SA_LD 200                                          // padded LDS row (bf16)

typedef __attribute__((ext_vector_type(8))) short short8;
typedef __attribute__((ext_vector_type(4))) float f32x4;
typedef __attribute__((ext_vector_type(4))) unsigned int u32x4;

__device__ inline unsigned short f2bf(float f) {
  unsigned u = __float_as_uint(f);
  u += 0x7FFFu + ((u >> 16) & 1u);   // RNE (used in tiny K0 only)
  return (unsigned short)(u >> 16);
}
// HW packed cvt: D = {bf16(b)<<16 | bf16(a)}, RNE — 1 VALU for 2 values.
__device__ inline unsigned cvtpk(float a, float b) {
  unsigned r;
  asm("v_cvt_pk_bf16_f32 %0, %1, %2" : "=v"(r) : "v"(a), "v"(b));
  return r;
}
__device__ inline unsigned short cvt1(float a) {
  unsigned r;
  asm("v_cvt_pk_bf16_f32 %0, %1, %1" : "=v"(r) : "v"(a));
  return (unsigned short)r;
}
__device__ inline float bf2f(unsigned short s) {
  return __uint_as_float(((unsigned)s) << 16);
}

// K0: WbTf in fragment order [wn][nt][kk][lane][8]; block 0 zeroes bcur.
__global__ __launch_bounds__(256) void wbt_kernel(
    const float* __restrict__ W, unsigned short* __restrict__ WbTf,
    int* __restrict__ bcur) {
  if (blockIdx.x == 0) {
    for (int i = threadIdx.x; i < NBUCKETS; i += 256) bcur[i] = 0;
  }
  int idx = blockIdx.x * 256 + threadIdx.x;
  if (idx >= 2 * 4 * 6 * 64 * 8) return;
  int j = idx & 7;
  int lane = (idx >> 3) & 63;
  int frag = idx >> 9;          // 0..47
  int kk = frag % 6, p = frag / 6;
  int wn = p >> 2, nt = p & 3;
  int col = wn * 64 + nt * 16 + (lane & 15);
  int k = kk * 32 + (lane >> 4) * 8 + j;
  WbTf[idx] = f2bf(W[k * HID + col]);
}

// K1: fused. Blocks 0..PC_NBLK-1: single-pass partition. Rest: MFMA GEMM x2.
#define SMEM_BYTES (32 * SA_LD * 2)   // 12800 >= 2*NBUCKETS*4 = 12504
__global__ __launch_bounds__(256) void gemm_pscatter_kernel(
    const float* __restrict__ F, const float* __restrict__ A,
    const unsigned short* __restrict__ WbTf, const float* __restrict__ bias,
    unsigned short* __restrict__ hb,
    const int* __restrict__ src, const int* __restrict__ dst,
    int* __restrict__ bcur, unsigned* __restrict__ edata, int nrows) {
  __shared__ __align__(16) char smem_raw[SMEM_BYTES];

  if (blockIdx.x < PC_NBLK) {
    // ---- partition path: single pass, edges buffered in registers ----
    int* lh = (int*)smem_raw;            // per-bucket: count, then global base
    int* lc = lh + NBUCKETS;             // running local cursor
    int bp = blockIdx.x;
    for (int i = threadIdx.x; i < NBUCKETS; i += 256) lh[i] = 0;
    __syncthreads();
    int base = bp * PC_CHUNK;
    int end = base + PC_CHUNK; if (end > N_EDGES) end = N_EDGES;
    int rd[EPT], rs[EPT];
#pragma unroll
    for (int k = 0; k < EPT; ++k) {
      int j = base + threadIdx.x + k * 256;
      if (j < end) {
        rd[k] = dst[j];
        rs[k] = src[j];
        atomicAdd(&lh[rd[k] >> BKT_SH], 1);
      } else {
        rd[k] = -1;
      }
    }
    __syncthreads();
    for (int i = threadIdx.x; i < NBUCKETS; i += 256) {
      int c = lh[i];
      lh[i] = c ? atomicAdd(&bcur[i], c) : 0;   // reserve contiguous slice
      lc[i] = 0;
    }
    __syncthreads();
#pragma unroll
    for (int k = 0; k < EPT; ++k) {
      if (rd[k] >= 0) {
        int bk = rd[k] >> BKT_SH, dl = rd[k] & (BKT_NODES - 1);
        int p = lh[bk] + atomicAdd(&lc[bk], 1);
        if (p < CAP)   // 22-sigma guard: memory safety on impossible overflow
          edata[(bk << 10) + p] = (unsigned)rs[k] | ((unsigned)dl << 16);
      }
    }
    return;
  }

  // ---- gemm path: 2 adjacent 32-row tiles, B-frags/bias loaded once ----
  unsigned short* sA = (unsigned short*)smem_raw;  // [32][SA_LD]
  const int gblk = blockIdx.x - PC_NBLK;
  const int tid = threadIdx.x;
  const int lane = tid & 63;
  const int wave = tid >> 6;
  const int wm = wave >> 1, wn = wave & 1;
  const int l15 = lane & 15, lg = lane >> 4;
  const int br0 = gblk * 64;
  const int br1 = br0 + 32;

  // Stage one 32-row tile: coalesced float4 loads, HW cvt_pk fp32->bf16
  // (r11: 1 VALU per pair), packed b64 LDS writes.
  auto stage = [&](int rowbase) {
#pragma unroll
    for (int it = 0; it < 4; ++it) {
      int i = tid + it * 256;
      int row = i >> 5, c4 = (i & 31) * 4;
      int crow = rowbase + row; crow = crow < nrows ? crow : (nrows - 1);
      float4 v = *(const float4*)(F + (size_t)crow * FDIM + c4);
      *(uint2*)(sA + row * SA_LD + c4) = make_uint2(cvtpk(v.x, v.y), cvtpk(v.z, v.w));
    }
#pragma unroll
    for (int it = 0; it < 2; ++it) {
      int i = tid + it * 256;
      int row = i >> 4, c4 = (i & 15) * 4;
      int crow = rowbase + row; crow = crow < nrows ? crow : (nrows - 1);
      float4 v = *(const float4*)(A + (size_t)crow * ADIM + c4);
      *(uint2*)(sA + row * SA_LD + FDIM + c4) = make_uint2(cvtpk(v.x, v.y), cvtpk(v.z, v.w));
    }
  };

  stage(br0);

  // B fragments: fully coalesced (fragment-ordered table, L2-resident);
  // loaded ONCE, reused by both tiles.
  short8 Bf[24];
#pragma unroll
  for (int nt = 0; nt < 4; ++nt)
#pragma unroll
    for (int kk = 0; kk < 6; ++kk)
      Bf[nt * 6 + kk] = *(const short8*)(
          WbTf + ((((wn * 4 + nt) * 6 + kk) << 9) + (lane << 3)));

  float bv[4];
#pragma unroll
  for (int nt = 0; nt < 4; ++nt) bv[nt] = bias[wn * 64 + nt * 16 + l15];

  __syncthreads();

  // A fragments tile0 from LDS (ds_read_b128)
  const int rowl = wm * 16 + l15;
  short8 Af[6];
#pragma unroll
  for (int kk = 0; kk < 6; ++kk)
    Af[kk] = *(const short8*)(sA + rowl * SA_LD + kk * 32 + lg * 8);

  const bool has2 = (br1 < nrows);          // block-uniform
  if (has2) {
    __syncthreads();                        // all Af0 reads done
    stage(br1);                             // loads in flight under tile0 MFMA
  }

  auto compute_store = [&](const short8* Afp, int rowbase) {
    f32x4 acc[4] = {{0,0,0,0},{0,0,0,0},{0,0,0,0},{0,0,0,0}};
#pragma unroll
    for (int nt = 0; nt < 4; ++nt)
#pragma unroll
      for (int kk = 0; kk < 6; ++kk)
        acc[nt] = __builtin_amdgcn_mfma_f32_16x16x32_bf16(
            Afp[kk], Bf[nt * 6 + kk], acc[nt], 0, 0, 0);
    const int rb = rowbase + wm * 16;
#pragma unroll
    for (int nt = 0; nt < 4; ++nt) {
      int col = wn * 64 + nt * 16 + l15;
#pragma unroll
      for (int q = 0; q < 4; ++q) {
        int row = rb + lg * 4 + q;
        if (row < nrows) {
          float v = fmaxf(acc[nt][q] + bv[nt], 0.f);
          hb[(size_t)row * HID + col] = cvt1(v);   // r11: HW cvt, 1 VALU
        }
      }
    }
  };

  compute_store(Af, br0);

  if (has2) {
    __syncthreads();                        // tile1 LDS writes visible
    short8 Af1[6];
#pragma unroll
    for (int kk = 0; kk < 6; ++kk)
      Af1[kk] = *(const short8*)(sA + rowl * SA_LD + kk * 32 + lg * 8);
    compute_store(Af1, br1);
  }
}

// K2: one-pass binning into stride-65 LDS bins + gather/mean.
// r10: nontemporal edata loads + out stores (protect hb's L2 residency).
#define EPT_A (CAP / 256)   // 4
__global__ __launch_bounds__(256) void bucket_agg_kernel(
    const unsigned short* __restrict__ hb, const int* __restrict__ bcur,
    const unsigned* __restrict__ edata, float* __restrict__ out) {
  int b = blockIdx.x;
  int nbase = b << BKT_SH;
  int nloc = N_NODES - nbase; if (nloc > BKT_NODES) nloc = BKT_NODES;
  int gb = b << 10;
  int cnt = bcur[b]; cnt = cnt < CAP ? cnt : CAP;
  int t = threadIdx.x, lane = t & 63, wave = t >> 6;
  int g = lane >> 4, l16 = lane & 15;

  __shared__ unsigned short ss[BKT_NODES * SS_LD];   // 32 bins, stride 65
  __shared__ int lcnt[BKT_NODES];

  if (t < BKT_NODES) lcnt[t] = 0;
  __syncthreads();
  // ONE pass: load edge, claim slot, store into bin. Bin stride 65 ->
  // store bank = ((dl+p)>>1)&31: <=2-way conflict (free).
#pragma unroll
  for (int k = 0; k < EPT_A; ++k) {
    int j = t + k * 256;
    if (j < cnt) {
      unsigned e = __builtin_nontemporal_load(edata + gb + j);
      int dl = e >> 16;
      int p = atomicAdd(&lcnt[dl], 1);
      if (p < DCAP)   // +12-sigma guard: memory-safe on impossible overflow
        ss[dl * SS_LD + p] = (unsigned short)(e & 0xFFFFu);
    }
  }
  __syncthreads();

  const unsigned short* hbl = hb + l16 * 8;   // lane's 16B column slice
  for (int n = wave; n < nloc; n += 4) {
    int d = lcnt[n];                          // true degree (divisor)
    int dc = d < DCAP ? d : DCAP;
    int s0 = n * SS_LD, s1 = s0 + dc;
    float acc[8] = {0, 0, 0, 0, 0, 0, 0, 0};
    int j = s0 + g;
    // 4 independent full-row gather chains per 16-lane group
    for (; j + 12 < s1; j += 16) {
      int e0 = ss[j], e1 = ss[j + 4], e2 = ss[j + 8], e3 = ss[j + 12];
      u32x4 v0 = *(const u32x4*)(hbl + (size_t)e0 * HID);
      u32x4 v1 = *(const u32x4*)(hbl + (size_t)e1 * HID);
      u32x4 v2 = *(const u32x4*)(hbl + (size_t)e2 * HID);
      u32x4 v3 = *(const u32x4*)(hbl + (size_t)e3 * HID);
#pragma unroll
      for (int i = 0; i < 4; ++i) {
        unsigned w0 = v0[i], w1 = v1[i], w2 = v2[i], w3 = v3[i];
        acc[2 * i]     += (bf2f((unsigned short)(w0 & 0xFFFFu))
                         + bf2f((unsigned short)(w1 & 0xFFFFu)))
                        + (bf2f((unsigned short)(w2 & 0xFFFFu))
                         + bf2f((unsigned short)(w3 & 0xFFFFu)));
        acc[2 * i + 1] += (bf2f((unsigned short)(w0 >> 16))
                         + bf2f((unsigned short)(w1 >> 16)))
                        + (bf2f((unsigned short)(w2 >> 16))
                         + bf2f((unsigned short)(w3 >> 16)));
      }
    }
    for (; j < s1; j += 4) {
      int e0 = ss[j];
      u32x4 v0 = *(const u32x4*)(hbl + (size_t)e0 * HID);
#pragma unroll
      for (int i = 0; i < 4; ++i) {
        unsigned w0 = v0[i];
        acc[2 * i]     += bf2f((unsigned short)(w0 & 0xFFFFu));
        acc[2 * i + 1] += bf2f((unsigned short)(w0 >> 16));
      }
    }
#pragma unroll
    for (int i = 0; i < 8; ++i) {
      acc[i] += __shfl_xor(acc[i], 16, 64);
      acc[i] += __shfl_xor(acc[i], 32, 64);
    }
    if (g == 0) {
      float inv = 1.0f / (float)(d > 1 ? d : 1);
      float* po = out + (size_t)(nbase + n) * HID + l16 * 8;
      f32x4 o0 = {acc[0] * inv, acc[1] * inv, acc[2] * inv, acc[3] * inv};
      f32x4 o1 = {acc[4] * inv, acc[5] * inv, acc[6] * inv, acc[7] * inv};
      __builtin_nontemporal_store(o0, (f32x4*)po);
      __builtin_nontemporal_store(o1, (f32x4*)(po + 4));
    }
  }
}

extern "C" void kernel_launch(void* const* d_in, const int* in_sizes, int n_in,
                              void* d_out, int out_size, void* d_ws, size_t ws_size,
                              hipStream_t stream) {
  const float* F   = (const float*)d_in[0];  // [50000,128]
  const float* A   = (const float*)d_in[1];  // [50000,64]
  const float* W   = (const float*)d_in[2];  // [192,128]
  const float* b   = (const float*)d_in[3];  // [128]
  const int*   src = (const int*)d_in[4];    // [800000]
  const int*   dst = (const int*)d_in[5];    // [800000]
  float* out = (float*)d_out;                // [50000,128]

  char* ws = (char*)d_ws;
  size_t off = 0;
  auto alloc = [&](size_t bytes) {
    char* p = ws + off;
    off += (bytes + 255) & ~(size_t)255;
    return p;
  };
  unsigned short* hb   = (unsigned short*)alloc((size_t)N_NODES * HID * 2); // 12.8 MB
  unsigned short* WbTf = (unsigned short*)alloc((size_t)HID * KDIM * 2);    // 48 KB
  int* bcur = (int*)alloc((size_t)NBUCKETS * sizeof(int));
  unsigned* edata = (unsigned*)alloc((size_t)NBUCKETS * CAP * sizeof(unsigned)); // 6.4 MB
  (void)ws_size;

  wbt_kernel<<<(KDIM * HID + 255) / 256, 256, 0, stream>>>(W, WbTf, bcur);
  gemm_pscatter_kernel<<<PC_NBLK + GEMM_NBLK, 256, 0, stream>>>(
      F, A, WbTf, b, hb, src, dst, bcur, edata, N_NODES);
  bucket_agg_kernel<<<NBUCKETS, 256, 0, stream>>>(hb, bcur, edata, out);
}